// Round 15
// baseline (206.075 us; speedup 1.0000x reference)
//
#include <hip/hip_runtime.h>
#include <hip/hip_fp16.h>
#include <math.h>

#define MROWS   65536
#define NCODES  1024
#define KD      256
#define MARGIN  0.25f

typedef unsigned short u16;
typedef __attribute__((ext_vector_type(8))) _Float16 hfrag;  // 8 fp16 = 4 VGPR
typedef __attribute__((ext_vector_type(4))) float f32x4;

// d_out bytes: [0,32M) Ah fp16 scratch (overwritten by quant writes later) |
//   quant floats [0,16777216) | idx floats at [64M, +256K).
// d_ws: [0,512K) Eh | [512K,+4K) esq | [640K) cnt | [640K+256,+256K) list
//       [1M,2M) embT | [2M,3M) tw (row*4: b, s2, bi, pad)
#define IOFF ((size_t)MROWS * KD)

// ---- asm-rounded fp32 add (contraction/reassociation-proof) ---------------
__device__ __forceinline__ float addrn(float a, float b) {
    float d; asm("v_add_f32 %0, %1, %2" : "=v"(d) : "v"(a), "v"(b)); return d;
}

// ---- exact VF8-IC4 sum of squares of a 256-row (R8-verified bits) ---------
__device__ __forceinline__ float sumsq_vf8ic4(const float* __restrict__ xr) {
    float a[4][8];
#pragma unroll
    for (int i = 0; i < 4; ++i)
#pragma unroll
        for (int l = 0; l < 8; ++l) a[i][l] = 0.f;
#pragma unroll
    for (int m = 0; m < 8; ++m)
#pragma unroll
        for (int i = 0; i < 4; ++i)
#pragma unroll
            for (int l = 0; l < 8; ++l) {
                float v = xr[m * 32 + i * 8 + l];
                a[i][l] = fmaf(v, v, a[i][l]);
            }
    float cc[8];
#pragma unroll
    for (int l = 0; l < 8; ++l)
        cc[l] = addrn(addrn(addrn(a[0][l], a[1][l]), a[2][l]), a[3][l]);
    float u0 = addrn(cc[0], cc[4]), u1 = addrn(cc[1], cc[5]);
    float u2 = addrn(cc[2], cc[6]), u3 = addrn(cc[3], cc[7]);
    return addrn(addrn(u0, u2), addrn(u1, u3));
}

// ------- pack x: fp32 [R][256] -> fragment-blocked fp16; zero cnt ----------
__global__ __launch_bounds__(256)
void vq_pack(const float* __restrict__ src, u16* __restrict__ dh,
             unsigned int* __restrict__ cnt) {
    if (blockIdx.x == 0 && threadIdx.x == 0) *cnt = 0;
    __shared__ __align__(16) float lx[16 * 260];
    const int t = threadIdx.x;
    const size_t base = (size_t)blockIdx.x * 16 * 256;
#pragma unroll
    for (int qq = 0; qq < 4; ++qq) {
        int i4 = qq * 256 + t;
        int row = i4 >> 6, col = (i4 & 63) * 4;
        *(float4*)(lx + row * 260 + col) = *(const float4*)(src + base + (size_t)i4 * 4);
    }
    __syncthreads();
#pragma unroll
    for (int i = 0; i < 2; ++i) {
        int s = t + 256 * i;
        int kb = s >> 6, lane = s & 63;
        int r = lane & 15, kg = lane >> 4;
        int k0 = kb * 32 + kg * 8;
        u16 vh[8];
#pragma unroll
        for (int j = 0; j < 8; ++j) {
            float v = lx[r * 260 + k0 + j];
            vh[j] = __half_as_ushort(__float2half(v));   // RNE
        }
        size_t off = (((size_t)blockIdx.x * 8 + kb) * 64 + lane) * 8;
        *(ulonglong2*)(dh + off) = *(ulonglong2*)vh;
    }
}

// ------- fused emb prep: pack Eh + esq (np-exact) + embT --------------------
__global__ __launch_bounds__(256)
void vq_prep_emb(const float* __restrict__ emb, u16* __restrict__ Eh,
                 float* __restrict__ esq, float* __restrict__ embT) {
    __shared__ float lx[64 * 257];
    const int t = threadIdx.x;
    const int c0 = blockIdx.x * 64;
    const size_t base = (size_t)c0 * 256;
#pragma unroll
    for (int qq = 0; qq < 16; ++qq) {
        int idx4 = qq * 256 + t;
        int row = idx4 >> 6, col4 = idx4 & 63;
        *(float4*)(lx + row * 257 + col4 * 4) = *(const float4*)(emb + base + (size_t)idx4 * 4);
    }
    __syncthreads();
    if (t < 64) esq[c0 + t] = sumsq_vf8ic4(lx + t * 257);
    // pack Eh fragments (4 row-groups x 8 kb x 64 lanes)
#pragma unroll
    for (int i = 0; i < 8; ++i) {
        int s = i * 256 + t;
        int fl = s >> 6, lane = s & 63;
        int rb_l = fl >> 3, kb = fl & 7;
        int r = rb_l * 16 + (lane & 15), kg = lane >> 4;
        int k0 = kb * 32 + kg * 8;
        u16 vh[8];
#pragma unroll
        for (int j = 0; j < 8; ++j)
            vh[j] = __half_as_ushort(__float2half(lx[r * 257 + k0 + j]));
        size_t off = (((size_t)(blockIdx.x * 4 + rb_l) * 8 + kb) * 64 + lane) * 8;
        *(ulonglong2*)(Eh + off) = *(ulonglong2*)vh;
    }
    // embT[k][c0+col] = emb[c0+col][k]
#pragma unroll
    for (int i = 0; i < 64; ++i) {
        int k = i * 4 + (t >> 6), col = t & 63;
        embT[(size_t)k * 1024 + c0 + col] = lx[col * 257 + k];
    }
}

// ------- MFMA fp16 GEMM: 8 waves, A in LDS, B reg-pipelined, in-kernel merge
__global__ __launch_bounds__(512, 4)
void vq_gemm(const u16* __restrict__ Ah, const u16* __restrict__ Eh,
             const float* __restrict__ esq, float* __restrict__ tw) {
    extern __shared__ u16 ldsA[];         // 64 KB: 64 A-frags x 512 u16
    const int t = threadIdx.x;
    const int wave = t >> 6, lane = t & 63;
    const int wm = wave >> 2, wn = wave & 3;
    const int q = lane >> 4, c = lane & 15;
    const int m0 = blockIdx.x * 128;
    const int mrb8 = blockIdx.x * 64;

    // stage entire A tile (64 frags) — single barrier, read-only after
#pragma unroll
    for (int u = 0; u < 8; ++u) {
        int f = wave * 8 + u;
        const u16* srcp = Ah + ((size_t)(mrb8 + f) * 64 + lane) * 8;
        __builtin_amdgcn_global_load_lds((const unsigned int*)srcp,
                                         (unsigned int*)(ldsA + f * 512), 16, 0, 0);
    }
    __syncthreads();

    // B frag: pass p = s>>3 covers 256 codes = 16 groups; group = p*16+wn*4+ni
    auto LOADB = [&](int s, hfrag* dst) {
        const int f0 = (s >> 3) * 128 + (wn * 4) * 8 + (s & 7);
#pragma unroll
        for (int ni = 0; ni < 4; ++ni)
            dst[ni] = *(const hfrag*)(Eh + (size_t)(f0 + ni * 8) * 512 + lane * 8);
    };
    auto LDA = [&](int s, hfrag* dst) {
        const int ks = s & 7;
#pragma unroll
        for (int mi = 0; mi < 4; ++mi)
            dst[mi] = *(const hfrag*)(ldsA + ((wm * 4 + mi) * 8 + ks) * 512 + lane * 8);
    };

    float b1[16], s2v[16], bi[16];
#pragma unroll
    for (int r = 0; r < 16; ++r) { b1[r] = INFINITY; s2v[r] = INFINITY; bi[r] = 0.f; }

    f32x4 acc[4][4];
#pragma unroll
    for (int mi = 0; mi < 4; ++mi)
#pragma unroll
        for (int ni = 0; ni < 4; ++ni) acc[mi][ni] = 0.f;

    hfrag bA[4], bB[4];
    LOADB(0, bA);
    LOADB(1, bB);

    for (int sp = 0; sp < 16; ++sp) {
        const int s0 = sp * 2, s1 = sp * 2 + 1;
        {
            hfrag nx[4];
            LOADB(s0 + 2 < 32 ? s0 + 2 : 0, nx);
            hfrag af[4];
            LDA(s0, af);
#pragma unroll
            for (int mi = 0; mi < 4; ++mi)
#pragma unroll
                for (int ni = 0; ni < 4; ++ni)
                    acc[mi][ni] = __builtin_amdgcn_mfma_f32_16x16x32_f16(af[mi], bA[ni], acc[mi][ni], 0, 0, 0);
#pragma unroll
            for (int ni = 0; ni < 4; ++ni) bA[ni] = nx[ni];
        }
        {
            hfrag nx[4];
            LOADB(s1 + 2 < 32 ? s1 + 2 : 0, nx);
            hfrag af[4];
            LDA(s1, af);
#pragma unroll
            for (int mi = 0; mi < 4; ++mi)
#pragma unroll
                for (int ni = 0; ni < 4; ++ni)
                    acc[mi][ni] = __builtin_amdgcn_mfma_f32_16x16x32_f16(af[mi], bB[ni], acc[mi][ni], 0, 0, 0);
#pragma unroll
            for (int ni = 0; ni < 4; ++ni) bB[ni] = nx[ni];
        }
        if ((s1 & 7) == 7) {
            const int p = s1 >> 3;
#pragma unroll
            for (int ni = 0; ni < 4; ++ni) {
                const int code = p * 256 + wn * 64 + ni * 16 + c;
                const float e2 = esq[code];
                const float ci = (float)code;
#pragma unroll
                for (int mi = 0; mi < 4; ++mi)
#pragma unroll
                    for (int j = 0; j < 4; ++j) {
                        const int r = mi * 4 + j;
                        float sc = fmaf(-2.f, acc[mi][ni][j], e2);
                        bool lt = sc < b1[r];
                        s2v[r] = fminf(s2v[r], lt ? b1[r] : sc);
                        if (lt) { b1[r] = sc; bi[r] = ci; }
                    }
            }
#pragma unroll
            for (int mi = 0; mi < 4; ++mi)
#pragma unroll
                for (int ni = 0; ni < 4; ++ni) acc[mi][ni] = 0.f;
        }
    }

    // merge the 16 c-lanes within each wave
#pragma unroll
    for (int r = 0; r < 16; ++r) {
#pragma unroll
        for (int mm = 1; mm < 16; mm <<= 1) {
            float ob = __shfl_xor(b1[r], mm, 64);
            float os = __shfl_xor(s2v[r], mm, 64);
            float oi = __shfl_xor(bi[r], mm, 64);
            if (ob < b1[r]) { s2v[r] = fminf(b1[r], os); b1[r] = ob; bi[r] = oi; }
            else            { s2v[r] = fminf(s2v[r], ob); }
        }
    }
    // cross-wave (wn) merge via LDS (A region is dead now)
    __syncthreads();
    float* sm = (float*)ldsA;   // 128 rows x 4 wn x 3 floats
    if (c == 0) {
#pragma unroll
        for (int mi = 0; mi < 4; ++mi)
#pragma unroll
            for (int j = 0; j < 4; ++j) {
                int r = mi * 4 + j;
                int row_l = wm * 64 + mi * 16 + q * 4 + j;
                sm[row_l * 12 + wn * 3 + 0] = b1[r];
                sm[row_l * 12 + wn * 3 + 1] = s2v[r];
                sm[row_l * 12 + wn * 3 + 2] = bi[r];
            }
    }
    __syncthreads();
    if (t < 128) {
        float b = INFINITY, s2 = INFINITY, bidx = 0.f;
#pragma unroll
        for (int w = 0; w < 4; ++w) {
            float ob = sm[t * 12 + w * 3 + 0];
            float os = sm[t * 12 + w * 3 + 1];
            float oi = sm[t * 12 + w * 3 + 2];
            if (ob < b) { s2 = fminf(b, os); b = ob; bidx = oi; }
            else        { s2 = fminf(s2, ob); }
        }
        size_t row = (size_t)(m0 + t);
        tw[row * 4 + 0] = b;
        tw[row * 4 + 1] = s2;
        tw[row * 4 + 2] = bidx;
    }
}

// ------- fused: flag near-ties + write idx + gather quant ------------------
__global__ __launch_bounds__(256)
void vq_flag_gather(const float* __restrict__ tw, const float* __restrict__ emb,
                    float* __restrict__ idxf, float* __restrict__ quant,
                    unsigned int* __restrict__ cnt, int* __restrict__ list) {
    __shared__ int idx_l[64];
    const int t = threadIdx.x;
    const int r0 = blockIdx.x * 64;
    if (t < 64) {
        int row = r0 + t;
        float b  = tw[(size_t)row * 4 + 0];
        float s2 = tw[(size_t)row * 4 + 1];
        int bidx = (int)tw[(size_t)row * 4 + 2];
        idxf[row] = (float)bidx;
        idx_l[t] = bidx;
        if (s2 - b < MARGIN) {
            unsigned int pos = atomicAdd(cnt, 1u);
            list[pos] = row;
        }
    }
    __syncthreads();
    const int lane = t & 63, w = t >> 6;
#pragma unroll
    for (int u = 0; u < 16; ++u) {
        int rl = u * 4 + w;
        int idx = idx_l[rl];
        *(float4*)(quant + (size_t)(r0 + rl) * 256 + lane * 4) =
            *(const float4*)(emb + (size_t)idx * 256 + lane * 4);
    }
}

// ------- exact refine: 8 rows/group, embT coalesced; fixes idx AND quant ---
__global__ __launch_bounds__(256)
void vq_refine1(const float* __restrict__ x, const float* __restrict__ emb,
                const float* __restrict__ embT, const float* __restrict__ esq,
                const int* __restrict__ list, const unsigned int* __restrict__ cnt,
                float* __restrict__ idxf, float* __restrict__ quant) {
    __shared__ __align__(16) float xs[8][260];
    __shared__ float xsq_s[8];
    __shared__ float lb[8][4];
    __shared__ int   li[8][4];
    __shared__ int   li2[8];
    const int t = threadIdx.x;
    const int wave = t >> 6, lane = t & 63;
    const unsigned int n = *cnt;
    float e2q[4];
#pragma unroll
    for (int qq = 0; qq < 4; ++qq) e2q[qq] = esq[qq * 256 + t];

    for (unsigned int g = blockIdx.x; g * 8u < n; g += gridDim.x) {
        const unsigned int r0 = g * 8u;
        const int nr = (int)min(8u, n - r0);
        __syncthreads();
#pragma unroll
        for (int u = 0; u < 2; ++u) {
            int s = u * 256 + t;
            int rr = s >> 6, l4 = s & 63;
            if (rr < nr) {
                int row = list[r0 + rr];
                *(float4*)(&xs[rr][l4 * 4]) = *(const float4*)(x + (size_t)row * 256 + l4 * 4);
            }
        }
        __syncthreads();
        if (t < nr) xsq_s[t] = sumsq_vf8ic4(&xs[t][0]);
        __syncthreads();

        float d[8][4];
#pragma unroll
        for (int r = 0; r < 8; ++r)
#pragma unroll
            for (int qq = 0; qq < 4; ++qq) d[r][qq] = 0.f;

        for (int kq = 0; kq < 64; ++kq) {
            float ev[4][4];
#pragma unroll
            for (int j = 0; j < 4; ++j)
#pragma unroll
                for (int qq = 0; qq < 4; ++qq)
                    ev[qq][j] = embT[(size_t)(kq * 4 + j) * 1024 + qq * 256 + t];
            float4 xf[8];
#pragma unroll
            for (int r = 0; r < 8; ++r) xf[r] = *(const float4*)(&xs[r][kq * 4]);
#pragma unroll
            for (int r = 0; r < 8; ++r)
#pragma unroll
                for (int qq = 0; qq < 4; ++qq) {
                    d[r][qq] = fmaf(xf[r].x, ev[qq][0], d[r][qq]);
                    d[r][qq] = fmaf(xf[r].y, ev[qq][1], d[r][qq]);
                    d[r][qq] = fmaf(xf[r].z, ev[qq][2], d[r][qq]);
                    d[r][qq] = fmaf(xf[r].w, ev[qq][3], d[r][qq]);
                }
        }
#pragma unroll
        for (int r = 0; r < 8; ++r) {
            float sv = INFINITY; int bc = 0x7fffffff;
#pragma unroll
            for (int qq = 0; qq < 4; ++qq) {   // ascending code order -> min idx on ties
                float s = addrn(fmaf(-2.f, d[r][qq], xsq_s[r]), e2q[qq]);
                if (s < sv) { sv = s; bc = qq * 256 + t; }
            }
#pragma unroll
            for (int mm = 1; mm < 64; mm <<= 1) {
                float ob = __shfl_xor(sv, mm, 64);
                int oi = __shfl_xor(bc, mm, 64);
                if (ob < sv || (ob == sv && oi < bc)) { sv = ob; bc = oi; }
            }
            if (lane == 0) { lb[r][wave] = sv; li[r][wave] = bc; }
        }
        __syncthreads();
        if (t < nr) {
            float best = lb[t][0]; int bix = li[t][0];
#pragma unroll
            for (int w = 1; w < 4; ++w) {
                float ob = lb[t][w]; int oi = li[t][w];
                if (ob < best || (ob == best && oi < bix)) { best = ob; bix = oi; }
            }
            idxf[list[r0 + t]] = (float)bix;
            li2[t] = bix;
        }
        __syncthreads();
        // fix the quant rows for corrected indices (2 rows per wave)
#pragma unroll
        for (int rr = 0; rr < 2; ++rr) {
            int rl = wave * 2 + rr;
            if (rl < nr) {
                int row = list[r0 + rl];
                int idx = li2[rl];
                *(float4*)(quant + (size_t)row * 256 + lane * 4) =
                    *(const float4*)(emb + (size_t)idx * 256 + lane * 4);
            }
        }
    }
}

extern "C" void kernel_launch(void* const* d_in, const int* in_sizes, int n_in,
                              void* d_out, int out_size, void* d_ws, size_t ws_size,
                              hipStream_t stream) {
    const float* x   = (const float*)d_in[0];
    const float* emb = (const float*)d_in[1];
    float* out  = (float*)d_out;
    float* idxf = out + IOFF;

    u16* Ah = (u16*)out;                          // [0, 32MB) scratch

    char* ws = (char*)d_ws;
    u16* Eh    = (u16*)(ws);
    float* esq = (float*)(ws + (512 << 10));
    unsigned int* cnt = (unsigned int*)(ws + (640 << 10));
    int* list  = (int*)(ws + (640 << 10) + 256);
    float* embT = (float*)(ws + (1 << 20));
    float* tw   = (float*)(ws + (2 << 20));

    vq_pack<<<dim3(MROWS / 16), dim3(256), 0, stream>>>(x, Ah, cnt);
    vq_prep_emb<<<dim3(16), dim3(256), 0, stream>>>(emb, Eh, esq, embT);
    vq_gemm<<<dim3(MROWS / 128), dim3(512), 65536, stream>>>(Ah, Eh, esq, tw);
    vq_flag_gather<<<dim3(MROWS / 64), dim3(256), 0, stream>>>(tw, emb, idxf, out, cnt, list);
    vq_refine1<<<dim3(512), dim3(256), 0, stream>>>(x, emb, embT, esq, list, cnt, idxf, out);
}

// Round 16
// 146.019 us; speedup vs baseline: 1.4113x; 1.4113x over previous
//
#include <hip/hip_runtime.h>
#include <hip/hip_fp16.h>
#include <math.h>

#define MROWS   65536
#define NCODES  1024
#define KD      256
#define MARGIN  0.25f

typedef unsigned short u16;
typedef __attribute__((ext_vector_type(8))) _Float16 hfrag;  // 8 fp16 = 4 VGPR
typedef __attribute__((ext_vector_type(4))) float f32x4;

// d_out bytes: [0,32M) Ah fp16 scratch | quant floats [0,64M) written at the end |
//   idx floats at [64M, +256K).
// d_ws: [0,512K) Eh (+64K overread slack into esq region, harmless) | [512K,+4K) esq |
//   [640K) cnt | [640K+256,+256K) list | [1M,2M) embT | [2M,3M) tw (row*4: b,s2,bi,pad)
#define IOFF ((size_t)MROWS * KD)

// ---- asm-rounded fp32 add (contraction/reassociation-proof) ---------------
__device__ __forceinline__ float addrn(float a, float b) {
    float d; asm("v_add_f32 %0, %1, %2" : "=v"(d) : "v"(a), "v"(b)); return d;
}

// ---- exact VF8-IC4 sum of squares of a 256-row (R8-verified bits) ---------
__device__ __forceinline__ float sumsq_vf8ic4(const float* __restrict__ xr) {
    float a[4][8];
#pragma unroll
    for (int i = 0; i < 4; ++i)
#pragma unroll
        for (int l = 0; l < 8; ++l) a[i][l] = 0.f;
#pragma unroll
    for (int m = 0; m < 8; ++m)
#pragma unroll
        for (int i = 0; i < 4; ++i)
#pragma unroll
            for (int l = 0; l < 8; ++l) {
                float v = xr[m * 32 + i * 8 + l];
                a[i][l] = fmaf(v, v, a[i][l]);
            }
    float cc[8];
#pragma unroll
    for (int l = 0; l < 8; ++l)
        cc[l] = addrn(addrn(addrn(a[0][l], a[1][l]), a[2][l]), a[3][l]);
    float u0 = addrn(cc[0], cc[4]), u1 = addrn(cc[1], cc[5]);
    float u2 = addrn(cc[2], cc[6]), u3 = addrn(cc[3], cc[7]);
    return addrn(addrn(u0, u2), addrn(u1, u3));
}

// ------- pack x: fp32 [R][256] -> fragment-blocked fp16; zero cnt ----------
__global__ __launch_bounds__(256)
void vq_pack(const float* __restrict__ src, u16* __restrict__ dh,
             unsigned int* __restrict__ cnt) {
    if (blockIdx.x == 0 && threadIdx.x == 0) *cnt = 0;
    __shared__ __align__(16) float lx[16 * 260];
    const int t = threadIdx.x;
    const size_t base = (size_t)blockIdx.x * 16 * 256;
#pragma unroll
    for (int qq = 0; qq < 4; ++qq) {
        int i4 = qq * 256 + t;
        int row = i4 >> 6, col = (i4 & 63) * 4;
        *(float4*)(lx + row * 260 + col) = *(const float4*)(src + base + (size_t)i4 * 4);
    }
    __syncthreads();
#pragma unroll
    for (int i = 0; i < 2; ++i) {
        int s = t + 256 * i;
        int kb = s >> 6, lane = s & 63;
        int r = lane & 15, kg = lane >> 4;
        int k0 = kb * 32 + kg * 8;
        u16 vh[8];
#pragma unroll
        for (int j = 0; j < 8; ++j) {
            float v = lx[r * 260 + k0 + j];
            vh[j] = __half_as_ushort(__float2half(v));   // RNE
        }
        size_t off = (((size_t)blockIdx.x * 8 + kb) * 64 + lane) * 8;
        *(ulonglong2*)(dh + off) = *(ulonglong2*)vh;
    }
}

// ------- fused emb prep: pack Eh (step-linear frag layout) + esq + embT ----
// frag(c,kb): g=c>>4, p=g>>3, wn=(g>>2)&1... g&7 -> wn=(g&7)>>2, ni=g&3
// frag = (p*8+kb)*8 + wn*4 + ni  => B-loads in gemm walk linearly in s=p*8+kb
__global__ __launch_bounds__(256)
void vq_prep_emb(const float* __restrict__ emb, u16* __restrict__ Eh,
                 float* __restrict__ esq, float* __restrict__ embT) {
    __shared__ float lx[64 * 257];
    const int t = threadIdx.x;
    const int c0 = blockIdx.x * 64;
    const size_t base = (size_t)c0 * 256;
#pragma unroll
    for (int qq = 0; qq < 16; ++qq) {
        int idx4 = qq * 256 + t;
        int row = idx4 >> 6, col4 = idx4 & 63;
        *(float4*)(lx + row * 257 + col4 * 4) = *(const float4*)(emb + base + (size_t)idx4 * 4);
    }
    __syncthreads();
    if (t < 64) esq[c0 + t] = sumsq_vf8ic4(lx + t * 257);
#pragma unroll
    for (int i = 0; i < 8; ++i) {
        int s = i * 256 + t;
        int fl = s >> 6, lane = s & 63;
        int rb_l = fl >> 3, kb = fl & 7;
        int g = blockIdx.x * 4 + rb_l;          // 16-code group, 0..63
        int p = g >> 3, gg = g & 7;
        int wn = gg >> 2, ni = gg & 3;
        int frag = (p * 8 + kb) * 8 + wn * 4 + ni;
        int r = rb_l * 16 + (lane & 15), kg = lane >> 4;
        int k0 = kb * 32 + kg * 8;
        u16 vh[8];
#pragma unroll
        for (int j = 0; j < 8; ++j)
            vh[j] = __half_as_ushort(__float2half(lx[r * 257 + k0 + j]));
        size_t off = ((size_t)frag * 64 + lane) * 8;
        *(ulonglong2*)(Eh + off) = *(ulonglong2*)vh;
    }
#pragma unroll
    for (int i = 0; i < 64; ++i) {
        int k = i * 4 + (t >> 6), col = t & 63;
        embT[(size_t)k * 1024 + c0 + col] = lx[col * 257 + k];
    }
}

// ------- MFMA fp16 GEMM: 64-row A-tile in LDS (32KB, 4 blk/CU), B linear ---
__global__ __launch_bounds__(256, 2)
void vq_gemm(const u16* __restrict__ Ah, const u16* __restrict__ Eh,
             const float* __restrict__ esq, float* __restrict__ tw) {
    __shared__ u16 ldsA[32 * 512];        // 32 KB
    const int t = threadIdx.x;
    const int wave = t >> 6, lane = t & 63;
    const int wm = wave >> 1, wn = wave & 1;
    const int q = lane >> 4, c = lane & 15;
    const int m0 = blockIdx.x * 64;

    // stage A tile (32 frags) — one barrier, read-only until the final merge
#pragma unroll
    for (int u = 0; u < 8; ++u) {
        int f = wave * 8 + u;
        const u16* srcp = Ah + ((size_t)(blockIdx.x * 32 + f) * 64 + lane) * 8;
        __builtin_amdgcn_global_load_lds((const unsigned int*)srcp,
                                         (unsigned int*)(ldsA + f * 512), 16, 0, 0);
    }
    __syncthreads();

    const u16* pB = Eh + (size_t)wn * 2048 + (size_t)lane * 8;  // + s*4096 elems
    const char* aB = (const char*)ldsA + wm * 16384 + lane * 16; // + mi*8192+ks*1024

    float b1[8], s2v[8], bi[8];
#pragma unroll
    for (int r = 0; r < 8; ++r) { b1[r] = INFINITY; s2v[r] = INFINITY; bi[r] = 0.f; }

    f32x4 acc[2][4];
#pragma unroll
    for (int mi = 0; mi < 2; ++mi)
#pragma unroll
        for (int ni = 0; ni < 4; ++ni) acc[mi][ni] = 0.f;

    hfrag bA[4], bB[4];
#pragma unroll
    for (int ni = 0; ni < 4; ++ni) bA[ni] = *(const hfrag*)(pB + 0 * 4096 + ni * 512);
#pragma unroll
    for (int ni = 0; ni < 4; ++ni) bB[ni] = *(const hfrag*)(pB + 1 * 4096 + ni * 512);

    for (int p = 0; p < 8; ++p) {
        const u16* pPp = pB + (size_t)p * 32768;   // frag base for s = p*8
#pragma unroll
        for (int ks = 0; ks < 8; ++ks) {
            hfrag af0 = *(const hfrag*)(aB + 0 * 8192 + ks * 1024);
            hfrag af1 = *(const hfrag*)(aB + 1 * 8192 + ks * 1024);
            if ((ks & 1) == 0) {
#pragma unroll
                for (int ni = 0; ni < 4; ++ni) {
                    acc[0][ni] = __builtin_amdgcn_mfma_f32_16x16x32_f16(af0, bA[ni], acc[0][ni], 0, 0, 0);
                    acc[1][ni] = __builtin_amdgcn_mfma_f32_16x16x32_f16(af1, bA[ni], acc[1][ni], 0, 0, 0);
                }
                // prefetch s+2 into the just-consumed buffer (overread at p=7 is in-ws slack)
#pragma unroll
                for (int ni = 0; ni < 4; ++ni)
                    bA[ni] = *(const hfrag*)(pPp + (ks + 2) * 4096 + ni * 512);
            } else {
#pragma unroll
                for (int ni = 0; ni < 4; ++ni) {
                    acc[0][ni] = __builtin_amdgcn_mfma_f32_16x16x32_f16(af0, bB[ni], acc[0][ni], 0, 0, 0);
                    acc[1][ni] = __builtin_amdgcn_mfma_f32_16x16x32_f16(af1, bB[ni], acc[1][ni], 0, 0, 0);
                }
#pragma unroll
                for (int ni = 0; ni < 4; ++ni)
                    bB[ni] = *(const hfrag*)(pPp + (ks + 2) * 4096 + ni * 512);
            }
        }
        // epilogue for this pass: 128 codes = wn*64 + ni*16 + c
#pragma unroll
        for (int ni = 0; ni < 4; ++ni) {
            const int code = p * 128 + wn * 64 + ni * 16 + c;
            const float e2 = esq[code];
            const float ci = (float)code;
#pragma unroll
            for (int mi = 0; mi < 2; ++mi)
#pragma unroll
                for (int j = 0; j < 4; ++j) {
                    const int r = mi * 4 + j;
                    float sc = fmaf(-2.f, acc[mi][ni][j], e2);
                    bool lt = sc < b1[r];
                    s2v[r] = fminf(s2v[r], lt ? b1[r] : sc);
                    if (lt) { b1[r] = sc; bi[r] = ci; }
                }
        }
#pragma unroll
        for (int mi = 0; mi < 2; ++mi)
#pragma unroll
            for (int ni = 0; ni < 4; ++ni) acc[mi][ni] = 0.f;
    }

    // merge across the 16 code-lanes (lane bits 0..3)
#pragma unroll
    for (int r = 0; r < 8; ++r) {
#pragma unroll
        for (int mm = 1; mm < 16; mm <<= 1) {
            float ob = __shfl_xor(b1[r], mm, 64);
            float os = __shfl_xor(s2v[r], mm, 64);
            float oi = __shfl_xor(bi[r], mm, 64);
            if (ob < b1[r]) { s2v[r] = fminf(b1[r], os); b1[r] = ob; bi[r] = oi; }
            else            { s2v[r] = fminf(s2v[r], ob); }
        }
    }
    // cross-wave (wn) merge via LDS (A region dead now)
    __syncthreads();
    float* sm = (float*)ldsA;   // 64 rows x 2 wn x 3 floats
    if (c == 0) {
#pragma unroll
        for (int mi = 0; mi < 2; ++mi)
#pragma unroll
            for (int j = 0; j < 4; ++j) {
                int r = mi * 4 + j;
                int row_l = wm * 32 + mi * 16 + q * 4 + j;
                sm[row_l * 6 + wn * 3 + 0] = b1[r];
                sm[row_l * 6 + wn * 3 + 1] = s2v[r];
                sm[row_l * 6 + wn * 3 + 2] = bi[r];
            }
    }
    __syncthreads();
    if (t < 64) {
        float b0 = sm[t * 6 + 0], s0 = sm[t * 6 + 1], i0 = sm[t * 6 + 2];
        float bb = sm[t * 6 + 3], s1 = sm[t * 6 + 4], i1 = sm[t * 6 + 5];
        float b, s2, bidx;
        if (b0 <= bb) { b = b0; bidx = i0; s2 = fminf(s0, bb); }
        else          { b = bb; bidx = i1; s2 = fminf(s1, b0); }
        size_t row = (size_t)(m0 + t);
        tw[row * 4 + 0] = b;
        tw[row * 4 + 1] = s2;
        tw[row * 4 + 2] = bidx;
    }
}

// ------- fused: flag near-ties + write idx + gather quant ------------------
__global__ __launch_bounds__(256)
void vq_flag_gather(const float* __restrict__ tw, const float* __restrict__ emb,
                    float* __restrict__ idxf, float* __restrict__ quant,
                    unsigned int* __restrict__ cnt, int* __restrict__ list) {
    __shared__ int idx_l[64];
    const int t = threadIdx.x;
    const int r0 = blockIdx.x * 64;
    if (t < 64) {
        int row = r0 + t;
        float b  = tw[(size_t)row * 4 + 0];
        float s2 = tw[(size_t)row * 4 + 1];
        int bidx = (int)tw[(size_t)row * 4 + 2];
        idxf[row] = (float)bidx;
        idx_l[t] = bidx;
        if (s2 - b < MARGIN) {
            unsigned int pos = atomicAdd(cnt, 1u);
            list[pos] = row;
        }
    }
    __syncthreads();
    const int lane = t & 63, w = t >> 6;
#pragma unroll
    for (int u = 0; u < 16; ++u) {
        int rl = u * 4 + w;
        int idx = idx_l[rl];
        *(float4*)(quant + (size_t)(r0 + rl) * 256 + lane * 4) =
            *(const float4*)(emb + (size_t)idx * 256 + lane * 4);
    }
}

// ------- exact refine: 8 rows/group, embT coalesced; fixes idx AND quant ---
__global__ __launch_bounds__(256)
void vq_refine1(const float* __restrict__ x, const float* __restrict__ emb,
                const float* __restrict__ embT, const float* __restrict__ esq,
                const int* __restrict__ list, const unsigned int* __restrict__ cnt,
                float* __restrict__ idxf, float* __restrict__ quant) {
    __shared__ __align__(16) float xs[8][260];
    __shared__ float xsq_s[8];
    __shared__ float lb[8][4];
    __shared__ int   li[8][4];
    __shared__ int   li2[8];
    const int t = threadIdx.x;
    const int wave = t >> 6, lane = t & 63;
    const unsigned int n = *cnt;
    float e2q[4];
#pragma unroll
    for (int qq = 0; qq < 4; ++qq) e2q[qq] = esq[qq * 256 + t];

    for (unsigned int g = blockIdx.x; g * 8u < n; g += gridDim.x) {
        const unsigned int r0 = g * 8u;
        const int nr = (int)min(8u, n - r0);
        __syncthreads();
#pragma unroll
        for (int u = 0; u < 2; ++u) {
            int s = u * 256 + t;
            int rr = s >> 6, l4 = s & 63;
            if (rr < nr) {
                int row = list[r0 + rr];
                *(float4*)(&xs[rr][l4 * 4]) = *(const float4*)(x + (size_t)row * 256 + l4 * 4);
            }
        }
        __syncthreads();
        if (t < nr) xsq_s[t] = sumsq_vf8ic4(&xs[t][0]);
        __syncthreads();

        float d[8][4];
#pragma unroll
        for (int r = 0; r < 8; ++r)
#pragma unroll
            for (int qq = 0; qq < 4; ++qq) d[r][qq] = 0.f;

        for (int kq = 0; kq < 64; ++kq) {
            float ev[4][4];
#pragma unroll
            for (int j = 0; j < 4; ++j)
#pragma unroll
                for (int qq = 0; qq < 4; ++qq)
                    ev[qq][j] = embT[(size_t)(kq * 4 + j) * 1024 + qq * 256 + t];
            float4 xf[8];
#pragma unroll
            for (int r = 0; r < 8; ++r) xf[r] = *(const float4*)(&xs[r][kq * 4]);
#pragma unroll
            for (int r = 0; r < 8; ++r)
#pragma unroll
                for (int qq = 0; qq < 4; ++qq) {
                    d[r][qq] = fmaf(xf[r].x, ev[qq][0], d[r][qq]);
                    d[r][qq] = fmaf(xf[r].y, ev[qq][1], d[r][qq]);
                    d[r][qq] = fmaf(xf[r].z, ev[qq][2], d[r][qq]);
                    d[r][qq] = fmaf(xf[r].w, ev[qq][3], d[r][qq]);
                }
        }
#pragma unroll
        for (int r = 0; r < 8; ++r) {
            float sv = INFINITY; int bc = 0x7fffffff;
#pragma unroll
            for (int qq = 0; qq < 4; ++qq) {   // ascending code order -> min idx on ties
                float s = addrn(fmaf(-2.f, d[r][qq], xsq_s[r]), e2q[qq]);
                if (s < sv) { sv = s; bc = qq * 256 + t; }
            }
#pragma unroll
            for (int mm = 1; mm < 64; mm <<= 1) {
                float ob = __shfl_xor(sv, mm, 64);
                int oi = __shfl_xor(bc, mm, 64);
                if (ob < sv || (ob == sv && oi < bc)) { sv = ob; bc = oi; }
            }
            if (lane == 0) { lb[r][wave] = sv; li[r][wave] = bc; }
        }
        __syncthreads();
        if (t < nr) {
            float best = lb[t][0]; int bix = li[t][0];
#pragma unroll
            for (int w = 1; w < 4; ++w) {
                float ob = lb[t][w]; int oi = li[t][w];
                if (ob < best || (ob == best && oi < bix)) { best = ob; bix = oi; }
            }
            idxf[list[r0 + t]] = (float)bix;
            li2[t] = bix;
        }
        __syncthreads();
#pragma unroll
        for (int rr = 0; rr < 2; ++rr) {
            int rl = wave * 2 + rr;
            if (rl < nr) {
                int row = list[r0 + rl];
                int idx = li2[rl];
                *(float4*)(quant + (size_t)row * 256 + lane * 4) =
                    *(const float4*)(emb + (size_t)idx * 256 + lane * 4);
            }
        }
    }
}

extern "C" void kernel_launch(void* const* d_in, const int* in_sizes, int n_in,
                              void* d_out, int out_size, void* d_ws, size_t ws_size,
                              hipStream_t stream) {
    const float* x   = (const float*)d_in[0];
    const float* emb = (const float*)d_in[1];
    float* out  = (float*)d_out;
    float* idxf = out + IOFF;

    u16* Ah = (u16*)out;                          // [0, 32MB) scratch

    char* ws = (char*)d_ws;
    u16* Eh    = (u16*)(ws);
    float* esq = (float*)(ws + (512 << 10));
    unsigned int* cnt = (unsigned int*)(ws + (640 << 10));
    int* list  = (int*)(ws + (640 << 10) + 256);
    float* embT = (float*)(ws + (1 << 20));
    float* tw   = (float*)(ws + (2 << 20));

    vq_pack<<<dim3(MROWS / 16), dim3(256), 0, stream>>>(x, Ah, cnt);
    vq_prep_emb<<<dim3(16), dim3(256), 0, stream>>>(emb, Eh, esq, embT);
    vq_gemm<<<dim3(MROWS / 64), dim3(256), 0, stream>>>(Ah, Eh, esq, tw);
    vq_flag_gather<<<dim3(MROWS / 64), dim3(256), 0, stream>>>(tw, emb, idxf, out, cnt, list);
    vq_refine1<<<dim3(512), dim3(256), 0, stream>>>(x, emb, embT, esq, list, cnt, idxf, out);
}